// Round 9
// baseline (50.872 us; speedup 1.0000x reference)
//
#include <hip/hip_runtime.h>
#include <cstddef>

// ===== DIAGNOSTIC ROUND 2 =====
// Round-6 config (best: 31.2 us) EXCEPT node_proj_kernel is dispatched THREE
// times (identical args -> identical A/B, deterministic). k2 once.
//   (dur_r9 - 31.2) / 2 = k1_warm.
// Combined with r8's k2_warm = 12.9 us, this fully splits the time budget
// {k1, k2, dispatch overhead} that rocprof's top-5 (all harness fills) hides.
//
// out[e,j] = tanh( A[row[e],j] + B[col[e],j] )
// A[n] = W0·u + W1·v,  B[n] = W0·v + W1·u,  u = x[n,0:64]+x[n,128:192], v = x[n,64:128]
// Karatsuba: s = (W0+W1)/2·(u+v), d = (W0-W1)/2·(u-v)  =>  A = s+d, B = s-d.

typedef float v4f __attribute__((ext_vector_type(4)));
typedef _Float16 v4h __attribute__((ext_vector_type(4)));

__device__ __forceinline__ float tanh_fast(float s) {
    float ex = __builtin_amdgcn_exp2f(s * 2.88539008f);
    return fmaf(-2.0f, __builtin_amdgcn_rcpf(ex + 1.0f), 1.0f);
}

// Kernel 1: per-node projections. 4 lanes (a quad) per node; 64 nodes per 256-thread block.
__global__ __launch_bounds__(256) void node_proj_kernel(
    const float* __restrict__ x, const float* __restrict__ W,
    _Float16* __restrict__ A, _Float16* __restrict__ B, int nnodes)
{
    __shared__ float ws[9 * 64];   // (W0+W1)/2
    __shared__ float wd[9 * 64];   // (W0-W1)/2
    for (int k = threadIdx.x; k < 9 * 64; k += 256) {
        int j = k >> 6, c = k & 63;
        float w0 = W[j * 128 + c], w1 = W[j * 128 + 64 + c];
        ws[k] = 0.5f * (w0 + w1);
        wd[k] = 0.5f * (w0 - w1);
    }
    __syncthreads();

    const int quad = threadIdx.x >> 2;            // 0..63: node within block
    const int q    = threadIdx.x & 3;             // lane within quad
    const int n    = blockIdx.x * 64 + quad;
    if (n >= nnodes) return;

    const float* xr = x + (size_t)n * 192;

    float ps[9], pd[9];
#pragma unroll
    for (int j = 0; j < 9; ++j) { ps[j] = 0.0f; pd[j] = 0.0f; }

#pragma unroll
    for (int ii = 0; ii < 4; ++ii) {
        const int c = 16 * ii + 4 * q;            // this lane's float4 channel offset
        v4f x0 = *(const v4f*)(xr + c);
        v4f x1 = *(const v4f*)(xr + 64 + c);
        v4f x2 = *(const v4f*)(xr + 128 + c);
        v4f u = x0 + x2;                          // sum-pool halves
        v4f su = u + x1;                          // u + v
        v4f du = u - x1;                          // u - v
#pragma unroll
        for (int j = 0; j < 9; ++j) {
            v4f a = *(const v4f*)(ws + j * 64 + c);
            v4f b = *(const v4f*)(wd + j * 64 + c);
            ps[j] = fmaf(a.x, su.x, ps[j]); ps[j] = fmaf(a.y, su.y, ps[j]);
            ps[j] = fmaf(a.z, su.z, ps[j]); ps[j] = fmaf(a.w, su.w, ps[j]);
            pd[j] = fmaf(b.x, du.x, pd[j]); pd[j] = fmaf(b.y, du.y, pd[j]);
            pd[j] = fmaf(b.z, du.z, pd[j]); pd[j] = fmaf(b.w, du.w, pd[j]);
        }
    }

#pragma unroll
    for (int j = 0; j < 9; ++j) {
        ps[j] += __shfl_xor(ps[j], 1); ps[j] += __shfl_xor(ps[j], 2);
        pd[j] += __shfl_xor(pd[j], 1); pd[j] += __shfl_xor(pd[j], 2);
    }

    _Float16* Ar = A + (size_t)n * 16;            // padded 32B records
    _Float16* Br = B + (size_t)n * 16;
    for (int j = q; j < 9; j += 4) {
        Ar[j] = (_Float16)(ps[j] + pd[j]);
        Br[j] = (_Float16)(ps[j] - pd[j]);
    }
}

// Kernel 2: FOUR lanes (a quad) per edge; quad-cooperative 8B-per-lane gathers
// of the 32B records; LDS transpose; coalesced v4f stores.
__global__ __launch_bounds__(256) void edge_map_kernel(
    const int* __restrict__ ei, const _Float16* __restrict__ A,
    const _Float16* __restrict__ B, float* __restrict__ out, int nedges)
{
    __shared__ float so[64 * 9];                  // 2.25 KB
    const int quad = threadIdx.x >> 2;            // 0..63: edge slot in block
    const int q    = threadIdx.x & 3;             // lane within quad
    const int e0   = blockIdx.x * 64;
    const int e    = e0 + quad;

    if (q < 3 && e < nedges) {                    // q==3 covers only pad -> masked off
        int row = ei[e];                          // 4-lane same-address: broadcast
        int col = ei[nedges + e];
        v4h a2 = *(const v4h*)(A + (size_t)row * 16 + 4 * q);
        v4h b2 = *(const v4h*)(B + (size_t)col * 16 + 4 * q);
        float* sl = so + quad * 9 + 4 * q;
#pragma unroll
        for (int i = 0; i < 4; ++i) {
            if (4 * q + i < 9)                    // q<2: all 4; q==2: only i==0
                sl[i] = tanh_fast((float)a2[i] + (float)b2[i]);
        }
    }
    __syncthreads();

    const int nval = (min(64, nedges - e0)) * 9;  // 576 for full blocks
    float* ob = out + (size_t)e0 * 9;
    int k4 = threadIdx.x * 4;
    if (k4 < nval) {
        if (k4 + 4 <= nval) {
            *(v4f*)(ob + k4) = *(const v4f*)(so + k4);   // 16B-aligned, coalesced
        } else {
            for (int m = k4; m < nval; ++m) ob[m] = so[m];
        }
    }
}

extern "C" void kernel_launch(void* const* d_in, const int* in_sizes, int n_in,
                              void* d_out, int out_size, void* d_ws, size_t ws_size,
                              hipStream_t stream) {
    const float* x  = (const float*)d_in[0];   // [N, 192] fp32
    const float* W  = (const float*)d_in[1];   // [9, 128] fp32
    const int*   ei = (const int*)d_in[2];     // [2, E] int32
    float* out = (float*)d_out;                // [E*9] fp32

    const int nnodes = in_sizes[0] / 192;
    const int nedges = in_sizes[2] / 2;

    _Float16* A = (_Float16*)d_ws;             // [nnodes*16] fp16 padded records
    _Float16* B = A + (size_t)nnodes * 16;     // [nnodes*16]

    const int blocks1 = (nnodes + 63) / 64;
    // Dispatch k1 THREE times (identical work/output) to measure k1's marginal
    // cost: (dur_r9 - dur_r6)/2 = k1_warm. Final A/B identical to single run.
    node_proj_kernel<<<blocks1, 256, 0, stream>>>(x, W, A, B, nnodes);
    node_proj_kernel<<<blocks1, 256, 0, stream>>>(x, W, A, B, nnodes);
    node_proj_kernel<<<blocks1, 256, 0, stream>>>(x, W, A, B, nnodes);

    const int blocks2 = (nedges + 63) / 64;    // 64 edges per 256-thread block
    edge_map_kernel<<<blocks2, 256, 0, stream>>>(ei, A, B, out, nedges);
}

// Round 11
// 33.758 us; speedup vs baseline: 1.5070x; 1.5070x over previous
//
#include <hip/hip_runtime.h>
#include <cstddef>

// Round-6 structure (best verified: 31.2 us) + ONE change: kernel 2's pure
// streaming traffic (ei loads, out stores) is non-temporal so the 3.2 MB
// fp16 A/B tables stay resident in each XCD's 4 MB L2 for the random gathers.
// k1 untouched.
//
// out[e,j] = tanh( A[row[e],j] + B[col[e],j] )
// A[n] = W0·u + W1·v,  B[n] = W0·v + W1·u,  u = x[n,0:64]+x[n,128:192], v = x[n,64:128]
// Karatsuba: s = (W0+W1)/2·(u+v), d = (W0-W1)/2·(u-v)  =>  A = s+d, B = s-d.

typedef float v4f __attribute__((ext_vector_type(4)));
typedef _Float16 v4h __attribute__((ext_vector_type(4)));

__device__ __forceinline__ float tanh_fast(float s) {
    // tanh(s) = 1 - 2/(e^{2s}+1); exp via exp2. Inf/0 limits give +-1, no clamp.
    float ex = __builtin_amdgcn_exp2f(s * 2.88539008f);
    return fmaf(-2.0f, __builtin_amdgcn_rcpf(ex + 1.0f), 1.0f);
}

// Kernel 1: per-node projections. 4 lanes (a quad) per node; 64 nodes per 256-thread block.
__global__ __launch_bounds__(256) void node_proj_kernel(
    const float* __restrict__ x, const float* __restrict__ W,
    _Float16* __restrict__ A, _Float16* __restrict__ B, int nnodes)
{
    __shared__ float ws[9 * 64];   // (W0+W1)/2
    __shared__ float wd[9 * 64];   // (W0-W1)/2
    for (int k = threadIdx.x; k < 9 * 64; k += 256) {
        int j = k >> 6, c = k & 63;
        float w0 = W[j * 128 + c], w1 = W[j * 128 + 64 + c];
        ws[k] = 0.5f * (w0 + w1);
        wd[k] = 0.5f * (w0 - w1);
    }
    __syncthreads();

    const int quad = threadIdx.x >> 2;            // 0..63: node within block
    const int q    = threadIdx.x & 3;             // lane within quad
    const int n    = blockIdx.x * 64 + quad;
    if (n >= nnodes) return;

    const float* xr = x + (size_t)n * 192;

    float ps[9], pd[9];
#pragma unroll
    for (int j = 0; j < 9; ++j) { ps[j] = 0.0f; pd[j] = 0.0f; }

#pragma unroll
    for (int ii = 0; ii < 4; ++ii) {
        const int c = 16 * ii + 4 * q;            // this lane's float4 channel offset
        v4f x0 = *(const v4f*)(xr + c);
        v4f x1 = *(const v4f*)(xr + 64 + c);
        v4f x2 = *(const v4f*)(xr + 128 + c);
        v4f u = x0 + x2;                          // sum-pool halves
        v4f su = u + x1;                          // u + v
        v4f du = u - x1;                          // u - v
#pragma unroll
        for (int j = 0; j < 9; ++j) {
            v4f a = *(const v4f*)(ws + j * 64 + c);
            v4f b = *(const v4f*)(wd + j * 64 + c);
            ps[j] = fmaf(a.x, su.x, ps[j]); ps[j] = fmaf(a.y, su.y, ps[j]);
            ps[j] = fmaf(a.z, su.z, ps[j]); ps[j] = fmaf(a.w, su.w, ps[j]);
            pd[j] = fmaf(b.x, du.x, pd[j]); pd[j] = fmaf(b.y, du.y, pd[j]);
            pd[j] = fmaf(b.z, du.z, pd[j]); pd[j] = fmaf(b.w, du.w, pd[j]);
        }
    }

    // quad butterfly reduce: all 4 lanes end with full 64-channel sums
#pragma unroll
    for (int j = 0; j < 9; ++j) {
        ps[j] += __shfl_xor(ps[j], 1); ps[j] += __shfl_xor(ps[j], 2);
        pd[j] += __shfl_xor(pd[j], 1); pd[j] += __shfl_xor(pd[j], 2);
    }

    _Float16* Ar = A + (size_t)n * 16;            // padded 32B records
    _Float16* Br = B + (size_t)n * 16;
    for (int j = q; j < 9; j += 4) {
        Ar[j] = (_Float16)(ps[j] + pd[j]);
        Br[j] = (_Float16)(ps[j] - pd[j]);
    }
}

// Kernel 2: FOUR lanes (a quad) per edge; quad-cooperative 8B-per-lane gathers
// of the 32B records; LDS transpose; coalesced v4f stores.
// ei loads and out stores are NON-TEMPORAL (evict-first) so they don't
// write-allocate/evict the A/B tables out of L2.
__global__ __launch_bounds__(256) void edge_map_kernel(
    const int* __restrict__ ei, const _Float16* __restrict__ A,
    const _Float16* __restrict__ B, float* __restrict__ out, int nedges)
{
    __shared__ float so[64 * 9];                  // 2.25 KB
    const int quad = threadIdx.x >> 2;            // 0..63: edge slot in block
    const int q    = threadIdx.x & 3;             // lane within quad
    const int e0   = blockIdx.x * 64;
    const int e    = e0 + quad;

    if (q < 3 && e < nedges) {                    // q==3 covers only pad -> masked off
        int row = __builtin_nontemporal_load(ei + e);          // streaming
        int col = __builtin_nontemporal_load(ei + nedges + e); // streaming
        v4h a2 = *(const v4h*)(A + (size_t)row * 16 + 4 * q);  // cached (table)
        v4h b2 = *(const v4h*)(B + (size_t)col * 16 + 4 * q);  // cached (table)
        float* sl = so + quad * 9 + 4 * q;
#pragma unroll
        for (int i = 0; i < 4; ++i) {
            if (4 * q + i < 9)                    // q<2: all 4; q==2: only i==0
                sl[i] = tanh_fast((float)a2[i] + (float)b2[i]);
        }
    }
    __syncthreads();

    const int nval = (min(64, nedges - e0)) * 9;  // 576 for full blocks
    float* ob = out + (size_t)e0 * 9;
    int k4 = threadIdx.x * 4;
    if (k4 < nval) {
        if (k4 + 4 <= nval) {
            __builtin_nontemporal_store(*(const v4f*)(so + k4), (v4f*)(ob + k4));
        } else {
            for (int m = k4; m < nval; ++m) ob[m] = so[m];
        }
    }
}

extern "C" void kernel_launch(void* const* d_in, const int* in_sizes, int n_in,
                              void* d_out, int out_size, void* d_ws, size_t ws_size,
                              hipStream_t stream) {
    const float* x  = (const float*)d_in[0];   // [N, 192] fp32
    const float* W  = (const float*)d_in[1];   // [9, 128] fp32
    const int*   ei = (const int*)d_in[2];     // [2, E] int32
    float* out = (float*)d_out;                // [E*9] fp32

    const int nnodes = in_sizes[0] / 192;
    const int nedges = in_sizes[2] / 2;

    _Float16* A = (_Float16*)d_ws;             // [nnodes*16] fp16 padded records
    _Float16* B = A + (size_t)nnodes * 16;     // [nnodes*16]

    const int blocks1 = (nnodes + 63) / 64;
    node_proj_kernel<<<blocks1, 256, 0, stream>>>(x, W, A, B, nnodes);

    const int blocks2 = (nedges + 63) / 64;    // 64 edges per 256-thread block
    edge_map_kernel<<<blocks2, 256, 0, stream>>>(ei, A, B, out, nedges);
}

// Round 12
// 30.155 us; speedup vs baseline: 1.6870x; 1.1195x over previous
//
#include <hip/hip_runtime.h>
#include <cstddef>

// Round-6 base (best verified: 31.2 us) + two mechanical fixes:
//  k1: packed v4h stores (compile-time lane indices) -> coalesced 8B stores,
//      full 32B record coverage (pads zeroed), no runtime-indexed reg arrays.
//  k2: 128 edges/block, 2 edges per quad -> 4 independent gathers in flight
//      per lane (2x MLP on the random table reads).
//
// out[e,j] = tanh( A[row[e],j] + B[col[e],j] )
// A[n] = W0·u + W1·v,  B[n] = W0·v + W1·u,  u = x[n,0:64]+x[n,128:192], v = x[n,64:128]
// Karatsuba: s = (W0+W1)/2·(u+v), d = (W0-W1)/2·(u-v)  =>  A = s+d, B = s-d.

typedef float v4f __attribute__((ext_vector_type(4)));
typedef _Float16 v4h __attribute__((ext_vector_type(4)));

__device__ __forceinline__ float tanh_fast(float s) {
    // tanh(s) = 1 - 2/(e^{2s}+1); exp via exp2. Inf/0 limits give +-1, no clamp.
    float ex = __builtin_amdgcn_exp2f(s * 2.88539008f);
    return fmaf(-2.0f, __builtin_amdgcn_rcpf(ex + 1.0f), 1.0f);
}

// Kernel 1: per-node projections. 4 lanes (a quad) per node; 64 nodes per 256-thread block.
__global__ __launch_bounds__(256) void node_proj_kernel(
    const float* __restrict__ x, const float* __restrict__ W,
    _Float16* __restrict__ A, _Float16* __restrict__ B, int nnodes)
{
    __shared__ float ws[9 * 64];   // (W0+W1)/2
    __shared__ float wd[9 * 64];   // (W0-W1)/2
    for (int k = threadIdx.x; k < 9 * 64; k += 256) {
        int j = k >> 6, c = k & 63;
        float w0 = W[j * 128 + c], w1 = W[j * 128 + 64 + c];
        ws[k] = 0.5f * (w0 + w1);
        wd[k] = 0.5f * (w0 - w1);
    }
    __syncthreads();

    const int quad = threadIdx.x >> 2;            // 0..63: node within block
    const int q    = threadIdx.x & 3;             // lane within quad
    const int n    = blockIdx.x * 64 + quad;
    if (n >= nnodes) return;

    const float* xr = x + (size_t)n * 192;

    float ps[9], pd[9];
#pragma unroll
    for (int j = 0; j < 9; ++j) { ps[j] = 0.0f; pd[j] = 0.0f; }

#pragma unroll
    for (int ii = 0; ii < 4; ++ii) {
        const int c = 16 * ii + 4 * q;            // this lane's float4 channel offset
        v4f x0 = *(const v4f*)(xr + c);
        v4f x1 = *(const v4f*)(xr + 64 + c);
        v4f x2 = *(const v4f*)(xr + 128 + c);
        v4f u = x0 + x2;                          // sum-pool halves
        v4f su = u + x1;                          // u + v
        v4f du = u - x1;                          // u - v
#pragma unroll
        for (int j = 0; j < 9; ++j) {
            v4f a = *(const v4f*)(ws + j * 64 + c);
            v4f b = *(const v4f*)(wd + j * 64 + c);
            ps[j] = fmaf(a.x, su.x, ps[j]); ps[j] = fmaf(a.y, su.y, ps[j]);
            ps[j] = fmaf(a.z, su.z, ps[j]); ps[j] = fmaf(a.w, su.w, ps[j]);
            pd[j] = fmaf(b.x, du.x, pd[j]); pd[j] = fmaf(b.y, du.y, pd[j]);
            pd[j] = fmaf(b.z, du.z, pd[j]); pd[j] = fmaf(b.w, du.w, pd[j]);
        }
    }

    // quad butterfly reduce: all 4 lanes end with full 64-channel sums
#pragma unroll
    for (int j = 0; j < 9; ++j) {
        ps[j] += __shfl_xor(ps[j], 1); ps[j] += __shfl_xor(ps[j], 2);
        pd[j] += __shfl_xor(pd[j], 1); pd[j] += __shfl_xor(pd[j], 2);
    }

    // Packed stores: lane q owns halves 4q..4q+3 of the 32B record.
    // All indices compile-time (no dynamic reg-array indexing / scratch).
    v4h av, bv;
    if (q == 0) {
        av[0] = (_Float16)(ps[0] + pd[0]); bv[0] = (_Float16)(ps[0] - pd[0]);
        av[1] = (_Float16)(ps[1] + pd[1]); bv[1] = (_Float16)(ps[1] - pd[1]);
        av[2] = (_Float16)(ps[2] + pd[2]); bv[2] = (_Float16)(ps[2] - pd[2]);
        av[3] = (_Float16)(ps[3] + pd[3]); bv[3] = (_Float16)(ps[3] - pd[3]);
    } else if (q == 1) {
        av[0] = (_Float16)(ps[4] + pd[4]); bv[0] = (_Float16)(ps[4] - pd[4]);
        av[1] = (_Float16)(ps[5] + pd[5]); bv[1] = (_Float16)(ps[5] - pd[5]);
        av[2] = (_Float16)(ps[6] + pd[6]); bv[2] = (_Float16)(ps[6] - pd[6]);
        av[3] = (_Float16)(ps[7] + pd[7]); bv[3] = (_Float16)(ps[7] - pd[7]);
    } else if (q == 2) {
        av[0] = (_Float16)(ps[8] + pd[8]); bv[0] = (_Float16)(ps[8] - pd[8]);
        av[1] = (_Float16)0.0f;            bv[1] = (_Float16)0.0f;
        av[2] = (_Float16)0.0f;            bv[2] = (_Float16)0.0f;
        av[3] = (_Float16)0.0f;            bv[3] = (_Float16)0.0f;
    } else {
        av[0] = av[1] = av[2] = av[3] = (_Float16)0.0f;
        bv[0] = bv[1] = bv[2] = bv[3] = (_Float16)0.0f;
    }
    *(v4h*)(A + (size_t)n * 16 + 4 * q) = av;     // coalesced 8B stores,
    *(v4h*)(B + (size_t)n * 16 + 4 * q) = bv;     // full 32B record covered
}

// Kernel 2: 128 edges per 256-thread block, TWO edges per quad -> 4 independent
// record gathers in flight per lane. Quad-cooperative 8B-per-lane gathers of the
// 32B records; LDS transpose; coalesced v4f stores.
__global__ __launch_bounds__(256) void edge_map_kernel(
    const int* __restrict__ ei, const _Float16* __restrict__ A,
    const _Float16* __restrict__ B, float* __restrict__ out, int nedges)
{
    __shared__ float so[128 * 9];                 // 4.5 KB
    const int quad = threadIdx.x >> 2;            // 0..63
    const int q    = threadIdx.x & 3;             // lane within quad
    const int e0   = blockIdx.x * 128;

    if (q < 3) {                                  // q==3: pad halves only
        const int e1 = min(e0 + quad,      nedges - 1);   // clamped, always safe
        const int e2 = min(e0 + 64 + quad, nedges - 1);
        int r1 = ei[e1], c1 = ei[nedges + e1];    // quad-broadcast loads
        int r2 = ei[e2], c2 = ei[nedges + e2];
        v4h a1 = *(const v4h*)(A + (size_t)r1 * 16 + 4 * q);
        v4h b1 = *(const v4h*)(B + (size_t)c1 * 16 + 4 * q);
        v4h a2 = *(const v4h*)(A + (size_t)r2 * 16 + 4 * q);
        v4h b2 = *(const v4h*)(B + (size_t)c2 * 16 + 4 * q);
        float* s1 = so + quad * 9 + 4 * q;
        float* s2 = so + (quad + 64) * 9 + 4 * q;
#pragma unroll
        for (int i = 0; i < 4; ++i) {
            if (4 * q + i < 9) {                  // q<2: all 4; q==2: only i==0
                s1[i] = tanh_fast((float)a1[i] + (float)b1[i]);
                s2[i] = tanh_fast((float)a2[i] + (float)b2[i]);
            }
        }
    }
    __syncthreads();

    const int nval = min(128, nedges - e0) * 9;   // 1152 for full blocks
    float* ob = out + (size_t)e0 * 9;
    for (int k4 = threadIdx.x * 4; k4 < nval; k4 += 1024) {
        if (k4 + 4 <= nval) {
            *(v4f*)(ob + k4) = *(const v4f*)(so + k4);   // coalesced
        } else {
            for (int m = k4; m < nval; ++m) ob[m] = so[m];
        }
    }
}

extern "C" void kernel_launch(void* const* d_in, const int* in_sizes, int n_in,
                              void* d_out, int out_size, void* d_ws, size_t ws_size,
                              hipStream_t stream) {
    const float* x  = (const float*)d_in[0];   // [N, 192] fp32
    const float* W  = (const float*)d_in[1];   // [9, 128] fp32
    const int*   ei = (const int*)d_in[2];     // [2, E] int32
    float* out = (float*)d_out;                // [E*9] fp32

    const int nnodes = in_sizes[0] / 192;
    const int nedges = in_sizes[2] / 2;

    _Float16* A = (_Float16*)d_ws;             // [nnodes*16] fp16 padded records
    _Float16* B = A + (size_t)nnodes * 16;     // [nnodes*16]

    const int blocks1 = (nnodes + 63) / 64;
    node_proj_kernel<<<blocks1, 256, 0, stream>>>(x, W, A, B, nnodes);

    const int blocks2 = (nedges + 127) / 128;  // 128 edges per 256-thread block
    edge_map_kernel<<<blocks2, 256, 0, stream>>>(ei, A, B, out, nedges);
}